// Round 7
// baseline (536.813 us; speedup 1.0000x reference)
//
#include <hip/hip_runtime.h>
#include <math.h>

#define NN 128
#define HH 128
#define LL 4097
#define PH 2049
// main kernel: 32 points per block, 256 threads, 65 tiles
#define BP2 32
#define NT2 65
// fallback: 64 points per block
#define BP 64
#define NTILE 33
// pre-split weight frags: 2 mats * 128 nets * 64 slots * 64 lanes * 16 B
#define WS_NEEDED (2u * 128u * 64u * 64u * 16u)

typedef short bf16x8 __attribute__((ext_vector_type(8)));
typedef float f32x4  __attribute__((ext_vector_type(4)));
typedef unsigned int u32;

// split f32 -> hi (bf16 by truncation) + lo (bf16 round-half-up of residual)
__device__ __forceinline__ void split1(float x, u32& hi, u32& lo) {
    u32 bx = __float_as_uint(x);
    hi = bx >> 16;
    float hf = __uint_as_float(bx & 0xffff0000u);
    float d  = x - hf;
    lo = (__float_as_uint(d) + 0x8000u) >> 16;
}

__device__ __forceinline__ f32x4 MF(bf16x8 a, bf16x8 b, f32x4 c) {
    return __builtin_amdgcn_mfma_f32_16x16x32_bf16(a, b, c, 0, 0, 0);
}

// Frag layout (W in global d_ws, X in LDS): frag fq = tile16*4 + kstep, hi/lo:
// slot = fq*2+hl; 16 B per lane at slot*1024 + lane*16.
// Lane l holds row/col = l&15, k = kstep*32 + (l>>4)*8 + e.

// ---------------- pre-pass: split w1,w2 into frag-linear hi/lo in d_ws --------
__global__ __launch_bounds__(512) void presplit(
    const float* __restrict__ w1, const float* __restrict__ w2, uint4* __restrict__ ws)
{
    const int b = blockIdx.x;            // 0..255 : m*128 + n
    const int m = b >> 7, n = b & 127;
    const float* wn = (m ? w2 : w1) + n * HH * HH;
    uint4* dst = ws + b * 4096;          // 64 slots * 64 lanes
    const int tid = threadIdx.x;
#pragma unroll
    for (int it = 0; it < 4; ++it) {
        const int s  = tid + it * 512;
        const int l  = s & 63;
        const int fq = s >> 6;           // rowtile*4 + ks
        const int ks = fq & 3, it7 = fq >> 2;
        const int i  = it7 * 16 + (l & 15);
        const int k0 = ks * 32 + (l >> 4) * 8;
        const float4* src = (const float4*)(wn + i * HH + k0);
        const float4 va = src[0], vb = src[1];
        const float v[8] = {va.x, va.y, va.z, va.w, vb.x, vb.y, vb.z, vb.w};
        u32 hd[4], ld_[4];
#pragma unroll
        for (int q = 0; q < 4; ++q) {
            u32 h0, l0, h1, l1;
            split1(v[2*q], h0, l0); split1(v[2*q+1], h1, l1);
            hd[q]  = h0 | (h1 << 16);
            ld_[q] = l0 | (l1 << 16);
        }
        dst[(fq*2 + 0)*64 + l] = make_uint4(hd[0], hd[1], hd[2], hd[3]);
        dst[(fq*2 + 1)*64 + l] = make_uint4(ld_[0], ld_[1], ld_[2], ld_[3]);
    }
}

// issue all 32 W-frag loads for this wave's row-half (independent, back-to-back)
__device__ __forceinline__ void loadW(const bf16x8* __restrict__ Wf, bf16x8 Wreg[32],
                                      int rw, int l) {
#pragma unroll
    for (int itl = 0; itl < 4; ++itl)
#pragma unroll
        for (int ks = 0; ks < 4; ++ks)
#pragma unroll
            for (int hl = 0; hl < 2; ++hl)
                Wreg[(itl*4 + ks)*2 + hl] = Wf[(((rw*4 + itl)*4 + ks)*2 + hl)*64 + l];
}

// one 128-row x 64-col x 128-K GEMM: A(W) from registers, B(X) from LDS
// wave (rw,cw): rows rw*64..+64, col-tiles ct = cw (h) and cw+2 (dh)
__device__ __forceinline__ void gemm_Wreg(const bf16x8 Wreg[32], const char* Xb,
                                          f32x4 acc[4][2], int cw, int l) {
    const bf16x8* Xf = (const bf16x8*)Xb;
#pragma unroll
    for (int ks = 0; ks < 4; ++ks) {
        bf16x8 Bh[2], Bl[2];
#pragma unroll
        for (int cg = 0; cg < 2; ++cg) {
            const int ct = cw + cg * 2;
            Bh[cg] = Xf[((ct*4 + ks)*2 + 0)*64 + l];
            Bl[cg] = Xf[((ct*4 + ks)*2 + 1)*64 + l];
        }
#pragma unroll
        for (int itl = 0; itl < 4; ++itl) {
            const bf16x8 Ah = Wreg[(itl*4 + ks)*2 + 0];
            const bf16x8 Al = Wreg[(itl*4 + ks)*2 + 1];
#pragma unroll
            for (int cg = 0; cg < 2; ++cg) {
                acc[itl][cg] = MF(Ah, Bh[cg], acc[itl][cg]);
                acc[itl][cg] = MF(Ah, Bl[cg], acc[itl][cg]);
                acc[itl][cg] = MF(Al, Bh[cg], acc[itl][cg]);
            }
        }
    }
}

__global__ __launch_bounds__(256, 5) void sofa_mfma4(
    const float* __restrict__ alpha,
    const float* __restrict__ w0, const float* __restrict__ w3,
    const float* __restrict__ b0, const float* __restrict__ b1,
    const float* __restrict__ b2, const float* __restrict__ b3,
    const float* __restrict__ sqrt_a,
    const uint4* __restrict__ ws,
    float* __restrict__ out)
{
    __shared__ char smem[32768];   // X frags: 4 ct * 4 ks * 2 hl * 1024 B
    char*  Xb  = smem;
    float* red = (float*)smem;     // reused after GEMM2 (128 floats)

    const int tile = blockIdx.x, n = blockIdx.y;
    const int tid = threadIdx.x;
    const int l   = tid & 63;
    const int w   = tid >> 6;                               // 0..3
    const int rw  = __builtin_amdgcn_readfirstlane(w & 1);  // row half
    const int cw  = __builtin_amdgcn_readfirstlane(w >> 1); // col pair, 0..1
    const int t   = l >> 4;

    const bf16x8* W1f = (const bf16x8*)(ws + n * 4096);
    const bf16x8* W2f = (const bf16x8*)(ws + (128 + n) * 4096);

    // ---- issue W1 prefetch into registers (hidden under layer0 VALU) ----
    bf16x8 Wreg[32];
    loadW(W1f, Wreg, rw, l);

    // ---- layer 0: elementwise, write X1 frags ----
    {
        const float* w0n = w0 + n * HH;
        const float* b0n = b0 + n * HH;
        const int c  = tid & 63;         // col: <32 h(point c), >=32 dh(point c-32)
        const int jb = tid >> 6;         // kstep 0..3
        int p = tile * BP2 + (c & 31);
        if (p > 2048) p = 2048;
        const float a = alpha[p];
        const bool isdh = c >= 32;
        const int ct = c >> 4;
#pragma unroll
        for (int g8 = 0; g8 < 4; ++g8) {
            const float4 wv4a = *(const float4*)(w0n + jb*32 + g8*8);
            const float4 wv4b = *(const float4*)(w0n + jb*32 + g8*8 + 4);
            const float4 bv4a = *(const float4*)(b0n + jb*32 + g8*8);
            const float4 bv4b = *(const float4*)(b0n + jb*32 + g8*8 + 4);
            const float wvv[8] = {wv4a.x,wv4a.y,wv4a.z,wv4a.w,wv4b.x,wv4b.y,wv4b.z,wv4b.w};
            const float bvv[8] = {bv4a.x,bv4a.y,bv4a.z,bv4a.w,bv4b.x,bv4b.y,bv4b.z,bv4b.w};
            u32 hd[4], ld_[4];
#pragma unroll
            for (int q = 0; q < 4; ++q) {
                float vv[2];
#pragma unroll
                for (int e = 0; e < 2; ++e) {
                    const float wv  = wvv[q*2 + e];
                    const float pre = fmaf(wv, a, bvv[q*2 + e]);
                    const bool  on  = pre > 0.f;
                    vv[e] = isdh ? (on ? wv : 0.f) : (on ? pre : 0.f);
                }
                u32 h0, l0, h1, l1;
                split1(vv[0], h0, l0); split1(vv[1], h1, l1);
                hd[q]  = h0 | (h1 << 16);
                ld_[q] = l0 | (l1 << 16);
            }
            const int lane = g8 * 16 + (c & 15);
            const int fq   = ct * 4 + jb;
            *(uint4*)(Xb + ((fq*2 + 0)*64 + lane)*16) = make_uint4(hd[0], hd[1], hd[2], hd[3]);
            *(uint4*)(Xb + ((fq*2 + 1)*64 + lane)*16) = make_uint4(ld_[0], ld_[1], ld_[2], ld_[3]);
        }
    }
    __syncthreads();

    // ---- GEMM 1 (W1 from registers) ----
    f32x4 acc[4][2];
#pragma unroll
    for (int i0 = 0; i0 < 4; ++i0)
#pragma unroll
        for (int c0 = 0; c0 < 2; ++c0) { f32x4 z = {0.f,0.f,0.f,0.f}; acc[i0][c0] = z; }
    __builtin_amdgcn_s_setprio(1);
    gemm_Wreg(Wreg, Xb, acc, cw, l);
    __builtin_amdgcn_s_setprio(0);

    // ---- issue W2 prefetch (hidden under transition VALU) ----
    loadW(W2f, Wreg, rw, l);

    // ---- transition: bias + relu + split/pack X2 in regs ----
    u32 px[4][2][2][2];  // [itl][cg][hl][dword]
    {
        const float* b1n = b1 + n * HH;
#pragma unroll
        for (int itl = 0; itl < 4; ++itl) {
            const int ibase = (rw*4 + itl)*16 + t*4;
            float hv[4], dv[4];
#pragma unroll
            for (int r = 0; r < 4; ++r) {
                const float pre = acc[itl][0][r] + b1n[ibase + r];
                const bool  on  = pre > 0.f;
                hv[r] = on ? pre : 0.f;
                dv[r] = on ? acc[itl][1][r] : 0.f;
            }
#pragma unroll
            for (int cg = 0; cg < 2; ++cg) {
                const float* vs = cg ? dv : hv;
                u32 a0,c0,a1,c1,a2,c2,a3,c3;
                split1(vs[0],a0,c0); split1(vs[1],a1,c1);
                split1(vs[2],a2,c2); split1(vs[3],a3,c3);
                px[itl][cg][0][0] = a0 | (a1 << 16);
                px[itl][cg][0][1] = a2 | (a3 << 16);
                px[itl][cg][1][0] = c0 | (c1 << 16);
                px[itl][cg][1][1] = c2 | (c3 << 16);
            }
        }
    }
    __syncthreads();   // all GEMM1 reads of X1 complete

    // ---- write X2 frags (pure intra-wave redistribution through LDS) ----
    {
#pragma unroll
        for (int itl = 0; itl < 4; ++itl) {
            const int IT   = rw*4 + itl;
            const int lane = ((IT & 1)*2 + (t >> 1))*16 + (l & 15);
            const int off8 = (t & 1)*8;
            const int ksn  = IT >> 1;
#pragma unroll
            for (int cg = 0; cg < 2; ++cg) {
                const int fq = (cw + cg*2)*4 + ksn;
#pragma unroll
                for (int hl = 0; hl < 2; ++hl) {
                    uint2 vv; vv.x = px[itl][cg][hl][0]; vv.y = px[itl][cg][hl][1];
                    *(uint2*)(Xb + ((fq*2 + hl)*64 + lane)*16 + off8) = vv;
                }
            }
        }
    }
    __syncthreads();

    // ---- GEMM 2 (W2 from registers) ----
    f32x4 acc2[4][2];
#pragma unroll
    for (int i0 = 0; i0 < 4; ++i0)
#pragma unroll
        for (int c0 = 0; c0 < 2; ++c0) { f32x4 z = {0.f,0.f,0.f,0.f}; acc2[i0][c0] = z; }
    __builtin_amdgcn_s_setprio(1);
    gemm_Wreg(Wreg, Xb, acc2, cw, l);
    __builtin_amdgcn_s_setprio(0);

    // ---- layer 3: bias+relu then reduce with w3 ----
    float sh = 0.f, sd = 0.f;
    {
        const float* b2n = b2 + n * HH;
        const float* w3n = w3 + n * HH;
#pragma unroll
        for (int itl = 0; itl < 4; ++itl) {
            const int ibase = (rw*4 + itl)*16 + t*4;
#pragma unroll
            for (int r = 0; r < 4; ++r) {
                const int   i   = ibase + r;
                const float pre = acc2[itl][0][r] + b2n[i];
                const bool  on  = pre > 0.f;
                const float hv  = on ? pre : 0.f;
                const float dv  = on ? acc2[itl][1][r] : 0.f;
                const float wv  = w3n[i];
                sh = fmaf(wv, hv, sh);
                sd = fmaf(wv, dv, sd);
            }
        }
    }
    sh += __shfl_xor(sh, 16); sh += __shfl_xor(sh, 32);
    sd += __shfl_xor(sd, 16); sd += __shfl_xor(sd, 32);
    __syncthreads();   // all GEMM2 X reads done -> reuse LDS as reduction buffer
    if (t == 0) {
        const int col = cw * 16 + (l & 15);     // point col 0..31
        red[rw * 32 + col]       = sh;
        red[64 + rw * 32 + col]  = sd;
    }
    __syncthreads();

    // ---- epilogue (32 threads): square + JVP + trig via __sinf + mirror identity ----
    if (tid < 32) {
        const float oo = b3[n] + red[tid] + red[32 + tid];
        const float d2 = red[64 + tid] + red[96 + tid];
        const float bb = oo * oo;
        const float db = 2.f * oo * d2;
        const float sa = sqrt_a[n];
        const float af = sa * sa;
        const int   NL = NN * LL;
        const int   k1 = tile * BP2 + tid;
        if (k1 < PH) {
            const float al = alpha[k1];
            const float sn = __sinf(al), cs = __cosf(al);
            const int base = n * LL + k1;
            out[base]          = af * (cs - 1.f);
            out[NL + base]     = bb * sn;
            out[2 * NL + base] = -af * sn;
            out[3 * NL + base] = fmaf(bb, cs, db * sn);
            // mirror half: alpha[4096-k1] = pi - alpha[k1] -> sin same, cos negated
            if (k1 <= PH - 2) {
                const int base2 = n * LL + (LL - 1) - k1;
                out[base2]          = af * (-cs - 1.f);
                out[NL + base2]     = bb * sn;
                out[2 * NL + base2] = -af * sn;
                out[3 * NL + base2] = fmaf(bb, -cs, -db * sn);
            }
        }
    }
}

// =================== fallback (round-4 kernel, used if ws too small) =========

__device__ __forceinline__ void stageW_fb(const float* __restrict__ wn, char* Wb, int tid) {
#pragma unroll
    for (int it = 0; it < 4; ++it) {
        const int s  = tid + it * 512;
        const int l  = s & 63;
        const int fq = s >> 6;
        const int ks = fq & 3, it7 = fq >> 2;
        const int i  = it7 * 16 + (l & 15);
        const int k0 = ks * 32 + (l >> 4) * 8;
        const float4* src = (const float4*)(wn + i * HH + k0);
        const float4 va = src[0], vb = src[1];
        const float v[8] = {va.x, va.y, va.z, va.w, vb.x, vb.y, vb.z, vb.w};
        u32 hd[4], ld_[4];
#pragma unroll
        for (int q = 0; q < 4; ++q) {
            u32 h0, l0, h1, l1;
            split1(v[2*q], h0, l0); split1(v[2*q+1], h1, l1);
            hd[q]  = h0 | (h1 << 16);
            ld_[q] = l0 | (l1 << 16);
        }
        *(uint4*)(Wb + (((fq*2)+0)*64 + l)*16) = make_uint4(hd[0], hd[1], hd[2], hd[3]);
        *(uint4*)(Wb + (((fq*2)+1)*64 + l)*16) = make_uint4(ld_[0], ld_[1], ld_[2], ld_[3]);
    }
}

__device__ __forceinline__ void gemm128_fb(const char* Wb, const char* Xb,
                                           f32x4 acc[4][2], int rw, int cw, int l) {
    const bf16x8* Wf = (const bf16x8*)Wb;
    const bf16x8* Xf = (const bf16x8*)Xb;
#pragma unroll
    for (int ks = 0; ks < 4; ++ks) {
        bf16x8 Bh[2], Bl[2];
#pragma unroll
        for (int cg = 0; cg < 2; ++cg) {
            const int ct = cw + cg * 4;
            Bh[cg] = Xf[((ct*4 + ks)*2 + 0)*64 + l];
            Bl[cg] = Xf[((ct*4 + ks)*2 + 1)*64 + l];
        }
#pragma unroll
        for (int itl = 0; itl < 4; ++itl) {
            const int IT = rw * 4 + itl;
            const bf16x8 Ah = Wf[((IT*4 + ks)*2 + 0)*64 + l];
            const bf16x8 Al = Wf[((IT*4 + ks)*2 + 1)*64 + l];
#pragma unroll
            for (int cg = 0; cg < 2; ++cg) {
                acc[itl][cg] = MF(Ah, Bh[cg], acc[itl][cg]);
                acc[itl][cg] = MF(Ah, Bl[cg], acc[itl][cg]);
                acc[itl][cg] = MF(Al, Bh[cg], acc[itl][cg]);
            }
        }
    }
}

__global__ __launch_bounds__(512, 2) void sofa_mfma_fb(
    const float* __restrict__ alpha,
    const float* __restrict__ w0, const float* __restrict__ w1,
    const float* __restrict__ w2, const float* __restrict__ w3,
    const float* __restrict__ b0, const float* __restrict__ b1,
    const float* __restrict__ b2, const float* __restrict__ b3,
    const float* __restrict__ sqrt_a,
    float* __restrict__ out)
{
    __shared__ char smem[131072];
    char* Wb = smem;
    char* Xb = smem + 65536;
    float* red = (float*)smem;

    const int tile = blockIdx.x, n = blockIdx.y;
    const int tid = threadIdx.x;
    const int l   = tid & 63;
    const int w   = tid >> 6;
    const int rw  = w & 1;
    const int cw  = w >> 1;
    const int t   = l >> 4;

    stageW_fb(w1 + n * HH * HH, Wb, tid);
    {
        const float* w0n = w0 + n * HH;
        const float* b0n = b0 + n * HH;
        const int c  = tid & 127;
        const int jb = tid >> 7;
        int p = tile * BP + (c & 63);
        if (p > 2048) p = 2048;
        const float a = alpha[p];
        const bool isdh = c >= 64;
        const int ct = c >> 4;
#pragma unroll
        for (int g8 = 0; g8 < 4; ++g8) {
            u32 hd[4], ld_[4];
#pragma unroll
            for (int q = 0; q < 4; ++q) {
                float vv[2];
#pragma unroll
                for (int e = 0; e < 2; ++e) {
                    const int j = jb * 32 + g8 * 8 + q * 2 + e;
                    const float wv  = w0n[j];
                    const float pre = fmaf(wv, a, b0n[j]);
                    const bool  on  = pre > 0.f;
                    vv[e] = isdh ? (on ? wv : 0.f) : (on ? pre : 0.f);
                }
                u32 h0, l0, h1, l1;
                split1(vv[0], h0, l0); split1(vv[1], h1, l1);
                hd[q]  = h0 | (h1 << 16);
                ld_[q] = l0 | (l1 << 16);
            }
            const int lane = g8 * 16 + (c & 15);
            const int fq   = ct * 4 + jb;
            *(uint4*)(Xb + ((fq*2 + 0)*64 + lane)*16) = make_uint4(hd[0], hd[1], hd[2], hd[3]);
            *(uint4*)(Xb + ((fq*2 + 1)*64 + lane)*16) = make_uint4(ld_[0], ld_[1], ld_[2], ld_[3]);
        }
    }
    __syncthreads();

    f32x4 acc[4][2];
#pragma unroll
    for (int i0 = 0; i0 < 4; ++i0)
#pragma unroll
        for (int c0 = 0; c0 < 2; ++c0) { f32x4 z = {0.f,0.f,0.f,0.f}; acc[i0][c0] = z; }
    gemm128_fb(Wb, Xb, acc, rw, cw, l);

    u32 px[4][2][2][2];
    {
        const float* b1n = b1 + n * HH;
#pragma unroll
        for (int itl = 0; itl < 4; ++itl) {
            const int ibase = (rw*4 + itl)*16 + t*4;
            float hv[4], dv[4];
#pragma unroll
            for (int r = 0; r < 4; ++r) {
                const float pre = acc[itl][0][r] + b1n[ibase + r];
                const bool  on  = pre > 0.f;
                hv[r] = on ? pre : 0.f;
                dv[r] = on ? acc[itl][1][r] : 0.f;
            }
#pragma unroll
            for (int cg = 0; cg < 2; ++cg) {
                const float* vs = cg ? dv : hv;
                u32 a0,c0,a1,c1,a2,c2,a3,c3;
                split1(vs[0],a0,c0); split1(vs[1],a1,c1);
                split1(vs[2],a2,c2); split1(vs[3],a3,c3);
                px[itl][cg][0][0] = a0 | (a1 << 16);
                px[itl][cg][0][1] = a2 | (a3 << 16);
                px[itl][cg][1][0] = c0 | (c1 << 16);
                px[itl][cg][1][1] = c2 | (c3 << 16);
            }
        }
    }
    __syncthreads();

    stageW_fb(w2 + n * HH * HH, Wb, tid);
    {
#pragma unroll
        for (int itl = 0; itl < 4; ++itl) {
            const int IT   = rw*4 + itl;
            const int lane = ((IT & 1)*2 + (t >> 1))*16 + (l & 15);
            const int off8 = (t & 1)*8;
            const int ksn  = IT >> 1;
#pragma unroll
            for (int cg = 0; cg < 2; ++cg) {
                const int fq = (cw + cg*4)*4 + ksn;
#pragma unroll
                for (int hl = 0; hl < 2; ++hl) {
                    uint2 vv; vv.x = px[itl][cg][hl][0]; vv.y = px[itl][cg][hl][1];
                    *(uint2*)(Xb + ((fq*2 + hl)*64 + lane)*16 + off8) = vv;
                }
            }
        }
    }
    __syncthreads();

    f32x4 acc2[4][2];
#pragma unroll
    for (int i0 = 0; i0 < 4; ++i0)
#pragma unroll
        for (int c0 = 0; c0 < 2; ++c0) { f32x4 z = {0.f,0.f,0.f,0.f}; acc2[i0][c0] = z; }
    gemm128_fb(Wb, Xb, acc2, rw, cw, l);

    float sh = 0.f, sd = 0.f;
    {
        const float* b2n = b2 + n * HH;
        const float* w3n = w3 + n * HH;
#pragma unroll
        for (int itl = 0; itl < 4; ++itl) {
            const int ibase = (rw*4 + itl)*16 + t*4;
#pragma unroll
            for (int r = 0; r < 4; ++r) {
                const int   i   = ibase + r;
                const float pre = acc2[itl][0][r] + b2n[i];
                const bool  on  = pre > 0.f;
                const float hv  = on ? pre : 0.f;
                const float dv  = on ? acc2[itl][1][r] : 0.f;
                const float wv  = w3n[i];
                sh = fmaf(wv, hv, sh);
                sd = fmaf(wv, dv, sd);
            }
        }
    }
    sh += __shfl_xor(sh, 16); sh += __shfl_xor(sh, 32);
    sd += __shfl_xor(sd, 16); sd += __shfl_xor(sd, 32);
    __syncthreads();
    if (t == 0) {
        const int p = cw * 16 + (l & 15);
        red[rw * 64 + p]        = sh;
        red[128 + rw * 64 + p]  = sd;
    }
    __syncthreads();

    if (tid < 64) {
        const float oo = b3[n] + red[tid] + red[64 + tid];
        const float d2 = red[128 + tid] + red[192 + tid];
        const float bb = oo * oo;
        const float db = 2.f * oo * d2;
        const float sa = sqrt_a[n];
        const float af = sa * sa;
        const int   NL = NN * LL;
        const int   k1 = tile * BP + tid;
        if (k1 < PH) {
            {
                const float al = alpha[k1];
                const float sn = sinf(al), cs = cosf(al);
                const int base = n * LL + k1;
                out[base]          = af * (cs - 1.f);
                out[NL + base]     = bb * sn;
                out[2 * NL + base] = -af * sn;
                out[3 * NL + base] = fmaf(bb, cs, db * sn);
            }
            if (k1 <= PH - 2) {
                const int   k2  = (LL - 1) - k1;
                const float al2 = alpha[k2];
                const float sn2 = sinf(al2), cs2 = cosf(al2);
                const int base2 = n * LL + k2;
                out[base2]          = af * (cs2 - 1.f);
                out[NL + base2]     = bb * sn2;
                out[2 * NL + base2] = -af * sn2;
                out[3 * NL + base2] = fmaf(bb, cs2, -db * sn2);
            }
        }
    }
}

extern "C" void kernel_launch(void* const* d_in, const int* in_sizes, int n_in,
                              void* d_out, int out_size, void* d_ws, size_t ws_size,
                              hipStream_t stream) {
    const float* alpha  = (const float*)d_in[0];
    const float* w0     = (const float*)d_in[1];
    const float* w1     = (const float*)d_in[2];
    const float* w2     = (const float*)d_in[3];
    const float* w3     = (const float*)d_in[4];
    const float* b0     = (const float*)d_in[5];
    const float* b1     = (const float*)d_in[6];
    const float* b2     = (const float*)d_in[7];
    const float* b3     = (const float*)d_in[8];
    const float* sqrt_a = (const float*)d_in[9];
    (void)in_sizes; (void)n_in; (void)out_size;

    if (ws_size >= (size_t)WS_NEEDED) {
        uint4* ws = (uint4*)d_ws;
        presplit<<<256, 512, 0, stream>>>(w1, w2, ws);
        dim3 grid(NT2, NN);
        sofa_mfma4<<<grid, 256, 0, stream>>>(alpha, w0, w3, b0, b1, b2, b3,
                                             sqrt_a, ws, (float*)d_out);
    } else {
        dim3 grid(NTILE, NN);
        sofa_mfma_fb<<<grid, 512, 0, stream>>>(alpha, w0, w1, w2, w3,
                                               b0, b1, b2, b3, sqrt_a,
                                               (float*)d_out);
    }
}

// Round 8
// 185.342 us; speedup vs baseline: 2.8963x; 2.8963x over previous
//
#include <hip/hip_runtime.h>
#include <math.h>

#define NN 128
#define HH 128
#define LL 4097
#define PH 2049
// main kernel: 32 points per block, 256 threads, 65 tiles
#define BP2 32
#define NT2 65
// fallback: 64 points per block
#define BP 64
#define NTILE 33
// pre-split weight frags: 2 mats * 128 nets * 64 slots * 64 lanes * 16 B
#define WS_NEEDED (2u * 128u * 64u * 64u * 16u)

typedef short bf16x8 __attribute__((ext_vector_type(8)));
typedef float f32x4  __attribute__((ext_vector_type(4)));
typedef unsigned int u32;

// split f32 -> hi (bf16 by truncation) + lo (bf16 round-half-up of residual)
__device__ __forceinline__ void split1(float x, u32& hi, u32& lo) {
    u32 bx = __float_as_uint(x);
    hi = bx >> 16;
    float hf = __uint_as_float(bx & 0xffff0000u);
    float d  = x - hf;
    lo = (__float_as_uint(d) + 0x8000u) >> 16;
}

__device__ __forceinline__ f32x4 MF(bf16x8 a, bf16x8 b, f32x4 c) {
    return __builtin_amdgcn_mfma_f32_16x16x32_bf16(a, b, c, 0, 0, 0);
}

// Frag layout (W in global d_ws, X in LDS): frag fq = tile16*4 + kstep, hi/lo:
// slot = fq*2+hl; 16 B per lane at slot*1024 + lane*16.
// Lane l holds row/col = l&15, k = kstep*32 + (l>>4)*8 + e.

// ---- pre-pass: split w1,w2 into frag-linear hi/lo in d_ws (coalesced reads) ----
__global__ __launch_bounds__(512) void presplit2(
    const float* __restrict__ w1, const float* __restrict__ w2, uint4* __restrict__ ws)
{
    __shared__ float lw[128 * 132];      // padded: bank = (4i + k) % 32 -> 2-way max
    const int b = blockIdx.x;            // 0..255 : m*128 + n
    const int m = b >> 7, n = b & 127;
    const float* wn = (m ? w2 : w1) + n * HH * HH;
    uint4* dst = ws + b * 4096;          // 64 slots * 64 lanes
    const int tid = threadIdx.x;

    // coalesced load of the whole 128x128 fp32 matrix into padded LDS
#pragma unroll
    for (int j = 0; j < 8; ++j) {
        const int flat = tid + j * 512;          // float4 index
        const float4 v4 = *(const float4*)(wn + flat * 4);
        const int row = flat >> 5;               // 32 float4 per row
        const int col = (flat & 31) * 4;
        *(float4*)(lw + row * 132 + col) = v4;
    }
    __syncthreads();

#pragma unroll
    for (int it = 0; it < 4; ++it) {
        const int s  = tid + it * 512;
        const int l  = s & 63;
        const int fq = s >> 6;           // rowtile*4 + ks
        const int ks = fq & 3, it7 = fq >> 2;
        const int i  = it7 * 16 + (l & 15);
        const int k0 = ks * 32 + (l >> 4) * 8;
        const float* src = lw + i * 132 + k0;
        u32 hd[4], ld_[4];
#pragma unroll
        for (int q = 0; q < 4; ++q) {
            u32 h0, l0, h1, l1;
            split1(src[2*q], h0, l0); split1(src[2*q+1], h1, l1);
            hd[q]  = h0 | (h1 << 16);
            ld_[q] = l0 | (l1 << 16);
        }
        dst[(fq*2 + 0)*64 + l] = make_uint4(hd[0], hd[1], hd[2], hd[3]);
        dst[(fq*2 + 1)*64 + l] = make_uint4(ld_[0], ld_[1], ld_[2], ld_[3]);
    }
}

// issue all 16 W-frag loads for this wave's row-QUARTER (rows rq*32..+32)
__device__ __forceinline__ void loadW16(const bf16x8* __restrict__ Wf, bf16x8 Wreg[16],
                                        int rq, int l) {
#pragma unroll
    for (int itl = 0; itl < 2; ++itl)
#pragma unroll
        for (int ks = 0; ks < 4; ++ks)
#pragma unroll
            for (int hl = 0; hl < 2; ++hl)
                Wreg[(itl*4 + ks)*2 + hl] = Wf[((((rq*2 + itl)*4 + ks)*2 + hl))*64 + l];
}

// one 32-row x 64-col x 128-K GEMM slice: A(W) from registers, B(X) from LDS
// acc[itl][ct]: itl = row tile (2), ct = col tile (4: 0,1=h  2,3=dh)
__device__ __forceinline__ void gemm_q(const bf16x8 Wreg[16], const char* Xb,
                                       f32x4 acc[2][4], int l) {
    const bf16x8* Xf = (const bf16x8*)Xb;
#pragma unroll
    for (int ks = 0; ks < 4; ++ks) {
        bf16x8 Bh[4], Bl[4];
#pragma unroll
        for (int ct = 0; ct < 4; ++ct) {
            Bh[ct] = Xf[((ct*4 + ks)*2 + 0)*64 + l];
            Bl[ct] = Xf[((ct*4 + ks)*2 + 1)*64 + l];
        }
#pragma unroll
        for (int itl = 0; itl < 2; ++itl) {
            const bf16x8 Ah = Wreg[(itl*4 + ks)*2 + 0];
            const bf16x8 Al = Wreg[(itl*4 + ks)*2 + 1];
#pragma unroll
            for (int ct = 0; ct < 4; ++ct) {
                acc[itl][ct] = MF(Ah, Bh[ct], acc[itl][ct]);
                acc[itl][ct] = MF(Ah, Bl[ct], acc[itl][ct]);
                acc[itl][ct] = MF(Al, Bh[ct], acc[itl][ct]);
            }
        }
    }
}

__global__ __launch_bounds__(256, 3) void sofa_mfma5(
    const float* __restrict__ alpha,
    const float* __restrict__ w0, const float* __restrict__ w3,
    const float* __restrict__ b0, const float* __restrict__ b1,
    const float* __restrict__ b2, const float* __restrict__ b3,
    const float* __restrict__ sqrt_a,
    const uint4* __restrict__ ws,
    float* __restrict__ out)
{
    __shared__ char smem[32768];   // X frags: 4 ct * 4 ks * 2 hl * 1024 B
    char*  Xb  = smem;
    float* red = (float*)smem;     // reused after GEMM2 (256 floats)

    const int tile = blockIdx.x, n = blockIdx.y;
    const int tid = threadIdx.x;
    const int l   = tid & 63;
    const int rq  = __builtin_amdgcn_readfirstlane(tid >> 6); // row quarter 0..3
    const int t   = l >> 4;

    const bf16x8* W1f = (const bf16x8*)(ws + n * 4096);
    const bf16x8* W2f = (const bf16x8*)(ws + (128 + n) * 4096);

    // ---- issue W1 prefetch into registers (hidden under layer0 VALU) ----
    bf16x8 Wreg[16];
    loadW16(W1f, Wreg, rq, l);

    // ---- layer 0: elementwise, write X1 frags ----
    {
        const float* w0n = w0 + n * HH;
        const float* b0n = b0 + n * HH;
        const int c  = tid & 63;         // col: <32 h(point c), >=32 dh(point c-32)
        const int jb = tid >> 6;         // kstep 0..3
        int p = tile * BP2 + (c & 31);
        if (p > 2048) p = 2048;
        const float a = alpha[p];
        const bool isdh = c >= 32;
        const int ct = c >> 4;
#pragma unroll
        for (int g8 = 0; g8 < 4; ++g8) {
            const float4 wv4a = *(const float4*)(w0n + jb*32 + g8*8);
            const float4 wv4b = *(const float4*)(w0n + jb*32 + g8*8 + 4);
            const float4 bv4a = *(const float4*)(b0n + jb*32 + g8*8);
            const float4 bv4b = *(const float4*)(b0n + jb*32 + g8*8 + 4);
            const float wvv[8] = {wv4a.x,wv4a.y,wv4a.z,wv4a.w,wv4b.x,wv4b.y,wv4b.z,wv4b.w};
            const float bvv[8] = {bv4a.x,bv4a.y,bv4a.z,bv4a.w,bv4b.x,bv4b.y,bv4b.z,bv4b.w};
            u32 hd[4], ld_[4];
#pragma unroll
            for (int q = 0; q < 4; ++q) {
                float vv[2];
#pragma unroll
                for (int e = 0; e < 2; ++e) {
                    const float wv  = wvv[q*2 + e];
                    const float pre = fmaf(wv, a, bvv[q*2 + e]);
                    const bool  on  = pre > 0.f;
                    vv[e] = isdh ? (on ? wv : 0.f) : (on ? pre : 0.f);
                }
                u32 h0, l0, h1, l1;
                split1(vv[0], h0, l0); split1(vv[1], h1, l1);
                hd[q]  = h0 | (h1 << 16);
                ld_[q] = l0 | (l1 << 16);
            }
            const int lane = g8 * 16 + (c & 15);
            const int fq   = ct * 4 + jb;
            *(uint4*)(Xb + ((fq*2 + 0)*64 + lane)*16) = make_uint4(hd[0], hd[1], hd[2], hd[3]);
            *(uint4*)(Xb + ((fq*2 + 1)*64 + lane)*16) = make_uint4(ld_[0], ld_[1], ld_[2], ld_[3]);
        }
    }
    __syncthreads();

    // ---- GEMM 1 (W1 from registers) ----
    f32x4 acc[2][4];
#pragma unroll
    for (int i0 = 0; i0 < 2; ++i0)
#pragma unroll
        for (int c0 = 0; c0 < 4; ++c0) { f32x4 z = {0.f,0.f,0.f,0.f}; acc[i0][c0] = z; }
    __builtin_amdgcn_s_setprio(1);
    gemm_q(Wreg, Xb, acc, l);
    __builtin_amdgcn_s_setprio(0);

    // ---- issue W2 prefetch (Wreg dead; hidden under transition VALU) ----
    loadW16(W2f, Wreg, rq, l);

    // ---- transition: bias + relu + split/pack X2 in regs ----
    // px[itl][c][hl]: uint2 = 4 bf16 (r=0..3) for h (which=0) and dh (which=1)
    u32 pxh[2][2][2][2], pxd[2][2][2][2];  // [itl][c][hl][dword]
    {
        const float* b1n = b1 + n * HH;
#pragma unroll
        for (int itl = 0; itl < 2; ++itl) {
            const int ibase = (rq*2 + itl)*16 + t*4;
#pragma unroll
            for (int c = 0; c < 2; ++c) {
                float hv[4], dv[4];
#pragma unroll
                for (int r = 0; r < 4; ++r) {
                    const float pre = acc[itl][c][r] + b1n[ibase + r];
                    const bool  on  = pre > 0.f;
                    hv[r] = on ? pre : 0.f;
                    dv[r] = on ? acc[itl][c + 2][r] : 0.f;
                }
                u32 a0,c0,a1,c1,a2,c2,a3,c3;
                split1(hv[0],a0,c0); split1(hv[1],a1,c1);
                split1(hv[2],a2,c2); split1(hv[3],a3,c3);
                pxh[itl][c][0][0] = a0 | (a1 << 16);
                pxh[itl][c][0][1] = a2 | (a3 << 16);
                pxh[itl][c][1][0] = c0 | (c1 << 16);
                pxh[itl][c][1][1] = c2 | (c3 << 16);
                split1(dv[0],a0,c0); split1(dv[1],a1,c1);
                split1(dv[2],a2,c2); split1(dv[3],a3,c3);
                pxd[itl][c][0][0] = a0 | (a1 << 16);
                pxd[itl][c][0][1] = a2 | (a3 << 16);
                pxd[itl][c][1][0] = c0 | (c1 << 16);
                pxd[itl][c][1][1] = c2 | (c3 << 16);
            }
        }
    }
    __syncthreads();   // all GEMM1 reads of X1 complete

    // ---- write X2 frags ----
    {
#pragma unroll
        for (int itl = 0; itl < 2; ++itl) {
            const int lane = (itl*2 + (t >> 1))*16 + (l & 15);
            const int off8 = (t & 1)*8;
#pragma unroll
            for (int c = 0; c < 2; ++c) {
#pragma unroll
                for (int hl = 0; hl < 2; ++hl) {
                    uint2 vh; vh.x = pxh[itl][c][hl][0]; vh.y = pxh[itl][c][hl][1];
                    *(uint2*)(Xb + (((c    )*4 + rq)*2 + hl)*1024 + lane*16 + off8) = vh;
                    uint2 vd; vd.x = pxd[itl][c][hl][0]; vd.y = pxd[itl][c][hl][1];
                    *(uint2*)(Xb + (((c + 2)*4 + rq)*2 + hl)*1024 + lane*16 + off8) = vd;
                }
            }
        }
    }
    __syncthreads();

    // ---- GEMM 2 (W2 from registers) ----
    f32x4 acc2[2][4];
#pragma unroll
    for (int i0 = 0; i0 < 2; ++i0)
#pragma unroll
        for (int c0 = 0; c0 < 4; ++c0) { f32x4 z = {0.f,0.f,0.f,0.f}; acc2[i0][c0] = z; }
    __builtin_amdgcn_s_setprio(1);
    gemm_q(Wreg, Xb, acc2, l);
    __builtin_amdgcn_s_setprio(0);

    // ---- layer 3: bias+relu then reduce with w3 (partial over this wave's 32 rows) ----
    float sh[2] = {0.f, 0.f}, sd[2] = {0.f, 0.f};
    {
        const float* b2n = b2 + n * HH;
        const float* w3n = w3 + n * HH;
#pragma unroll
        for (int itl = 0; itl < 2; ++itl) {
            const int ibase = (rq*2 + itl)*16 + t*4;
#pragma unroll
            for (int r = 0; r < 4; ++r) {
                const int   i  = ibase + r;
                const float bv = b2n[i];
                const float wv = w3n[i];
#pragma unroll
                for (int c = 0; c < 2; ++c) {
                    const float pre = acc2[itl][c][r] + bv;
                    const bool  on  = pre > 0.f;
                    sh[c] = fmaf(wv, on ? pre : 0.f,              sh[c]);
                    sd[c] = fmaf(wv, on ? acc2[itl][c + 2][r] : 0.f, sd[c]);
                }
            }
        }
    }
#pragma unroll
    for (int c = 0; c < 2; ++c) {
        sh[c] += __shfl_xor(sh[c], 16); sh[c] += __shfl_xor(sh[c], 32);
        sd[c] += __shfl_xor(sd[c], 16); sd[c] += __shfl_xor(sd[c], 32);
    }
    __syncthreads();   // all GEMM2 X reads done -> reuse LDS as reduction buffer
    if (l < 16) {
#pragma unroll
        for (int c = 0; c < 2; ++c) {
            red[rq * 32 + c * 16 + l]        = sh[c];
            red[128 + rq * 32 + c * 16 + l]  = sd[c];
        }
    }
    __syncthreads();

    // ---- epilogue (32 threads): square + JVP + trig via __sinf + mirror identity ----
    if (tid < 32) {
        float oo = b3[n], d2 = 0.f;
#pragma unroll
        for (int q = 0; q < 4; ++q) {
            oo += red[q * 32 + tid];
            d2 += red[128 + q * 32 + tid];
        }
        const float bb = oo * oo;
        const float db = 2.f * oo * d2;
        const float sa = sqrt_a[n];
        const float af = sa * sa;
        const int   NL = NN * LL;
        const int   k1 = tile * BP2 + tid;
        if (k1 < PH) {
            const float al = alpha[k1];
            const float sn = __sinf(al), cs = __cosf(al);
            const int base = n * LL + k1;
            out[base]          = af * (cs - 1.f);
            out[NL + base]     = bb * sn;
            out[2 * NL + base] = -af * sn;
            out[3 * NL + base] = fmaf(bb, cs, db * sn);
            // mirror half: alpha[4096-k1] = pi - alpha[k1] -> sin same, cos negated
            if (k1 <= PH - 2) {
                const int base2 = n * LL + (LL - 1) - k1;
                out[base2]          = af * (-cs - 1.f);
                out[NL + base2]     = bb * sn;
                out[2 * NL + base2] = -af * sn;
                out[3 * NL + base2] = fmaf(bb, -cs, -db * sn);
            }
        }
    }
}

// =================== fallback (round-4 kernel, used if ws too small) =========

__device__ __forceinline__ void stageW_fb(const float* __restrict__ wn, char* Wb, int tid) {
#pragma unroll
    for (int it = 0; it < 4; ++it) {
        const int s  = tid + it * 512;
        const int l  = s & 63;
        const int fq = s >> 6;
        const int ks = fq & 3, it7 = fq >> 2;
        const int i  = it7 * 16 + (l & 15);
        const int k0 = ks * 32 + (l >> 4) * 8;
        const float4* src = (const float4*)(wn + i * HH + k0);
        const float4 va = src[0], vb = src[1];
        const float v[8] = {va.x, va.y, va.z, va.w, vb.x, vb.y, vb.z, vb.w};
        u32 hd[4], ld_[4];
#pragma unroll
        for (int q = 0; q < 4; ++q) {
            u32 h0, l0, h1, l1;
            split1(v[2*q], h0, l0); split1(v[2*q+1], h1, l1);
            hd[q]  = h0 | (h1 << 16);
            ld_[q] = l0 | (l1 << 16);
        }
        *(uint4*)(Wb + (((fq*2)+0)*64 + l)*16) = make_uint4(hd[0], hd[1], hd[2], hd[3]);
        *(uint4*)(Wb + (((fq*2)+1)*64 + l)*16) = make_uint4(ld_[0], ld_[1], ld_[2], ld_[3]);
    }
}

__device__ __forceinline__ void gemm128_fb(const char* Wb, const char* Xb,
                                           f32x4 acc[4][2], int rw, int cw, int l) {
    const bf16x8* Wf = (const bf16x8*)Wb;
    const bf16x8* Xf = (const bf16x8*)Xb;
#pragma unroll
    for (int ks = 0; ks < 4; ++ks) {
        bf16x8 Bh[2], Bl[2];
#pragma unroll
        for (int cg = 0; cg < 2; ++cg) {
            const int ct = cw + cg * 4;
            Bh[cg] = Xf[((ct*4 + ks)*2 + 0)*64 + l];
            Bl[cg] = Xf[((ct*4 + ks)*2 + 1)*64 + l];
        }
#pragma unroll
        for (int itl = 0; itl < 4; ++itl) {
            const int IT = rw * 4 + itl;
            const bf16x8 Ah = Wf[((IT*4 + ks)*2 + 0)*64 + l];
            const bf16x8 Al = Wf[((IT*4 + ks)*2 + 1)*64 + l];
#pragma unroll
            for (int cg = 0; cg < 2; ++cg) {
                acc[itl][cg] = MF(Ah, Bh[cg], acc[itl][cg]);
                acc[itl][cg] = MF(Ah, Bl[cg], acc[itl][cg]);
                acc[itl][cg] = MF(Al, Bh[cg], acc[itl][cg]);
            }
        }
    }
}

__global__ __launch_bounds__(512, 2) void sofa_mfma_fb(
    const float* __restrict__ alpha,
    const float* __restrict__ w0, const float* __restrict__ w1,
    const float* __restrict__ w2, const float* __restrict__ w3,
    const float* __restrict__ b0, const float* __restrict__ b1,
    const float* __restrict__ b2, const float* __restrict__ b3,
    const float* __restrict__ sqrt_a,
    float* __restrict__ out)
{
    __shared__ char smem[131072];
    char* Wb = smem;
    char* Xb = smem + 65536;
    float* red = (float*)smem;

    const int tile = blockIdx.x, n = blockIdx.y;
    const int tid = threadIdx.x;
    const int l   = tid & 63;
    const int w   = tid >> 6;
    const int rw  = w & 1;
    const int cw  = w >> 1;
    const int t   = l >> 4;

    stageW_fb(w1 + n * HH * HH, Wb, tid);
    {
        const float* w0n = w0 + n * HH;
        const float* b0n = b0 + n * HH;
        const int c  = tid & 127;
        const int jb = tid >> 7;
        int p = tile * BP + (c & 63);
        if (p > 2048) p = 2048;
        const float a = alpha[p];
        const bool isdh = c >= 64;
        const int ct = c >> 4;
#pragma unroll
        for (int g8 = 0; g8 < 4; ++g8) {
            u32 hd[4], ld_[4];
#pragma unroll
            for (int q = 0; q < 4; ++q) {
                float vv[2];
#pragma unroll
                for (int e = 0; e < 2; ++e) {
                    const int j = jb * 32 + g8 * 8 + q * 2 + e;
                    const float wv  = w0n[j];
                    const float pre = fmaf(wv, a, b0n[j]);
                    const bool  on  = pre > 0.f;
                    vv[e] = isdh ? (on ? wv : 0.f) : (on ? pre : 0.f);
                }
                u32 h0, l0, h1, l1;
                split1(vv[0], h0, l0); split1(vv[1], h1, l1);
                hd[q]  = h0 | (h1 << 16);
                ld_[q] = l0 | (l1 << 16);
            }
            const int lane = g8 * 16 + (c & 15);
            const int fq   = ct * 4 + jb;
            *(uint4*)(Xb + ((fq*2 + 0)*64 + lane)*16) = make_uint4(hd[0], hd[1], hd[2], hd[3]);
            *(uint4*)(Xb + ((fq*2 + 1)*64 + lane)*16) = make_uint4(ld_[0], ld_[1], ld_[2], ld_[3]);
        }
    }
    __syncthreads();

    f32x4 acc[4][2];
#pragma unroll
    for (int i0 = 0; i0 < 4; ++i0)
#pragma unroll
        for (int c0 = 0; c0 < 2; ++c0) { f32x4 z = {0.f,0.f,0.f,0.f}; acc[i0][c0] = z; }
    gemm128_fb(Wb, Xb, acc, rw, cw, l);

    u32 px[4][2][2][2];
    {
        const float* b1n = b1 + n * HH;
#pragma unroll
        for (int itl = 0; itl < 4; ++itl) {
            const int ibase = (rw*4 + itl)*16 + t*4;
            float hv[4], dv[4];
#pragma unroll
            for (int r = 0; r < 4; ++r) {
                const float pre = acc[itl][0][r] + b1n[ibase + r];
                const bool  on  = pre > 0.f;
                hv[r] = on ? pre : 0.f;
                dv[r] = on ? acc[itl][1][r] : 0.f;
            }
#pragma unroll
            for (int cg = 0; cg < 2; ++cg) {
                const float* vs = cg ? dv : hv;
                u32 a0,c0,a1,c1,a2,c2,a3,c3;
                split1(vs[0],a0,c0); split1(vs[1],a1,c1);
                split1(vs[2],a2,c2); split1(vs[3],a3,c3);
                px[itl][cg][0][0] = a0 | (a1 << 16);
                px[itl][cg][0][1] = a2 | (a3 << 16);
                px[itl][cg][1][0] = c0 | (c1 << 16);
                px[itl][cg][1][1] = c2 | (c3 << 16);
            }
        }
    }
    __syncthreads();

    stageW_fb(w2 + n * HH * HH, Wb, tid);
    {
#pragma unroll
        for (int itl = 0; itl < 4; ++itl) {
            const int IT   = rw*4 + itl;
            const int lane = ((IT & 1)*2 + (t >> 1))*16 + (l & 15);
            const int off8 = (t & 1)*8;
            const int ksn  = IT >> 1;
#pragma unroll
            for (int cg = 0; cg < 2; ++cg) {
                const int fq = (cw + cg*4)*4 + ksn;
#pragma unroll
                for (int hl = 0; hl < 2; ++hl) {
                    uint2 vv; vv.x = px[itl][cg][hl][0]; vv.y = px[itl][cg][hl][1];
                    *(uint2*)(Xb + ((fq*2 + hl)*64 + lane)*16 + off8) = vv;
                }
            }
        }
    }
    __syncthreads();

    f32x4 acc2[4][2];
#pragma unroll
    for (int i0 = 0; i0 < 4; ++i0)
#pragma unroll
        for (int c0 = 0; c0 < 2; ++c0) { f32x4 z = {0.f,0.f,0.f,0.f}; acc2[i0][c0] = z; }
    gemm128_fb(Wb, Xb, acc2, rw, cw, l);

    float sh = 0.f, sd = 0.f;
    {
        const float* b2n = b2 + n * HH;
        const float* w3n = w3 + n * HH;
#pragma unroll
        for (int itl = 0; itl < 4; ++itl) {
            const int ibase = (rw*4 + itl)*16 + t*4;
#pragma unroll
            for (int r = 0; r < 4; ++r) {
                const int   i   = ibase + r;
                const float pre = acc2[itl][0][r] + b2n[i];
                const bool  on  = pre > 0.f;
                const float hv  = on ? pre : 0.f;
                const float dv  = on ? acc2[itl][1][r] : 0.f;
                const float wv  = w3n[i];
                sh = fmaf(wv, hv, sh);
                sd = fmaf(wv, dv, sd);
            }
        }
    }
    sh += __shfl_xor(sh, 16); sh += __shfl_xor(sh, 32);
    sd += __shfl_xor(sd, 16); sd += __shfl_xor(sd, 32);
    __syncthreads();
    if (t == 0) {
        const int p = cw * 16 + (l & 15);
        red[rw * 64 + p]        = sh;
        red[128 + rw * 64 + p]  = sd;
    }
    __syncthreads();

    if (tid < 64) {
        const float oo = b3[n] + red[tid] + red[64 + tid];
        const float d2 = red[128 + tid] + red[192 + tid];
        const float bb = oo * oo;
        const float db = 2.f * oo * d2;
        const float sa = sqrt_a[n];
        const float af = sa * sa;
        const int   NL = NN * LL;
        const int   k1 = tile * BP + tid;
        if (k1 < PH) {
            {
                const float al = alpha[k1];
                const float sn = sinf(al), cs = cosf(al);
                const int base = n * LL + k1;
                out[base]          = af * (cs - 1.f);
                out[NL + base]     = bb * sn;
                out[2 * NL + base] = -af * sn;
                out[3 * NL + base] = fmaf(bb, cs, db * sn);
            }
            if (k1 <= PH - 2) {
                const int   k2  = (LL - 1) - k1;
                const float al2 = alpha[k2];
                const float sn2 = sinf(al2), cs2 = cosf(al2);
                const int base2 = n * LL + k2;
                out[base2]          = af * (cs2 - 1.f);
                out[NL + base2]     = bb * sn2;
                out[2 * NL + base2] = -af * sn2;
                out[3 * NL + base2] = fmaf(bb, cs2, -db * sn2);
            }
        }
    }
}

extern "C" void kernel_launch(void* const* d_in, const int* in_sizes, int n_in,
                              void* d_out, int out_size, void* d_ws, size_t ws_size,
                              hipStream_t stream) {
    const float* alpha  = (const float*)d_in[0];
    const float* w0     = (const float*)d_in[1];
    const float* w1     = (const float*)d_in[2];
    const float* w2     = (const float*)d_in[3];
    const float* w3     = (const float*)d_in[4];
    const float* b0     = (const float*)d_in[5];
    const float* b1     = (const float*)d_in[6];
    const float* b2     = (const float*)d_in[7];
    const float* b3     = (const float*)d_in[8];
    const float* sqrt_a = (const float*)d_in[9];
    (void)in_sizes; (void)n_in; (void)out_size;

    if (ws_size >= (size_t)WS_NEEDED) {
        uint4* ws = (uint4*)d_ws;
        presplit2<<<256, 512, 0, stream>>>(w1, w2, ws);
        dim3 grid(NT2, NN);
        sofa_mfma5<<<grid, 256, 0, stream>>>(alpha, w0, w3, b0, b1, b2, b3,
                                             sqrt_a, ws, (float*)d_out);
    } else {
        dim3 grid(NTILE, NN);
        sofa_mfma_fb<<<grid, 512, 0, stream>>>(alpha, w0, w1, w2, w3,
                                               b0, b1, b2, b3, sqrt_a,
                                               (float*)d_out);
    }
}

// Round 9
// 179.530 us; speedup vs baseline: 2.9901x; 1.0324x over previous
//
#include <hip/hip_runtime.h>
#include <math.h>

#define NN 128
#define HH 128
#define LL 4097
#define PH 2049
// main kernel: 32 points per block, 256 threads, 65 tiles
#define BP2 32
#define NT2 65
// fallback: 64 points per block
#define BP 64
#define NTILE 33
// pre-split weight frags: 2 mats * 128 nets * 64 slots * 64 lanes * 16 B
#define WS_NEEDED (2u * 128u * 64u * 64u * 16u)

typedef short bf16x8 __attribute__((ext_vector_type(8)));
typedef float f32x4  __attribute__((ext_vector_type(4)));
typedef unsigned int u32;

// ---- scalar split (fallback kernel only): hi=trunc, lo=round(residual) ----
__device__ __forceinline__ void split1(float x, u32& hi, u32& lo) {
    u32 bx = __float_as_uint(x);
    hi = bx >> 16;
    float hf = __uint_as_float(bx & 0xffff0000u);
    float d  = x - hf;
    lo = (__float_as_uint(d) + 0x8000u) >> 16;
}

// ---- HW pair conversion: r = bf16(a) | bf16(b)<<16 (RNE) ----
__device__ __forceinline__ u32 cvtpk(float a, float b) {
    u32 r;
    asm("v_cvt_pk_bf16_f32 %0, %1, %2" : "=v"(r) : "v"(a), "v"(b));
    return r;
}

// pair split: hpk = packed hi(RNE), lpk = packed lo = RNE(x - hi)
// residual x-hi is exact in fp32 (Sterbenz: hi within 2^-9 of x)
__device__ __forceinline__ void split_pair(float x0, float x1, u32& hpk, u32& lpk) {
    hpk = cvtpk(x0, x1);
    const float h0 = __uint_as_float(hpk << 16);
    const float h1 = __uint_as_float(hpk & 0xffff0000u);
    lpk = cvtpk(x0 - h0, x1 - h1);
}

__device__ __forceinline__ f32x4 MF(bf16x8 a, bf16x8 b, f32x4 c) {
    return __builtin_amdgcn_mfma_f32_16x16x32_bf16(a, b, c, 0, 0, 0);
}

// Frag layout (W in global d_ws, X in LDS): frag fq = tile16*4 + kstep, hi/lo:
// slot = fq*2+hl; 16 B per lane at slot*1024 + lane*16.
// Lane l holds row/col = l&15, k = kstep*32 + (l>>4)*8 + e.

// ---- pre-pass: split w1,w2 into frag-linear hi/lo in d_ws (coalesced reads) ----
__global__ __launch_bounds__(512) void presplit2(
    const float* __restrict__ w1, const float* __restrict__ w2, uint4* __restrict__ ws)
{
    __shared__ float lw[128 * 132];      // padded: 2-way conflicts max
    const int b = blockIdx.x;            // 0..255 : m*128 + n
    const int m = b >> 7, n = b & 127;
    const float* wn = (m ? w2 : w1) + n * HH * HH;
    uint4* dst = ws + b * 4096;          // 64 slots * 64 lanes
    const int tid = threadIdx.x;

    // coalesced load of the whole 128x128 fp32 matrix into padded LDS
#pragma unroll
    for (int j = 0; j < 8; ++j) {
        const int flat = tid + j * 512;          // float4 index
        const float4 v4 = *(const float4*)(wn + flat * 4);
        const int row = flat >> 5;               // 32 float4 per row
        const int col = (flat & 31) * 4;
        *(float4*)(lw + row * 132 + col) = v4;
    }
    __syncthreads();

#pragma unroll
    for (int it = 0; it < 4; ++it) {
        const int s  = tid + it * 512;
        const int l  = s & 63;
        const int fq = s >> 6;           // rowtile*4 + ks
        const int ks = fq & 3, it7 = fq >> 2;
        const int i  = it7 * 16 + (l & 15);
        const int k0 = ks * 32 + (l >> 4) * 8;
        const float* src = lw + i * 132 + k0;
        u32 hd[4], ld_[4];
#pragma unroll
        for (int q = 0; q < 4; ++q)
            split_pair(src[2*q], src[2*q+1], hd[q], ld_[q]);
        dst[(fq*2 + 0)*64 + l] = make_uint4(hd[0], hd[1], hd[2], hd[3]);
        dst[(fq*2 + 1)*64 + l] = make_uint4(ld_[0], ld_[1], ld_[2], ld_[3]);
    }
}

// issue all 16 W-frag loads for this wave's row-QUARTER (rows rq*32..+32)
__device__ __forceinline__ void loadW16(const bf16x8* __restrict__ Wf, bf16x8 Wreg[16],
                                        int rq, int l) {
#pragma unroll
    for (int itl = 0; itl < 2; ++itl)
#pragma unroll
        for (int ks = 0; ks < 4; ++ks)
#pragma unroll
            for (int hl = 0; hl < 2; ++hl)
                Wreg[(itl*4 + ks)*2 + hl] = Wf[((((rq*2 + itl)*4 + ks)*2 + hl))*64 + l];
}

// one 32-row x 64-col x 128-K GEMM slice: A(W) from registers, B(X) from LDS
// acc[itl][ct]: itl = row tile (2), ct = col tile (4: 0,1=h  2,3=dh)
__device__ __forceinline__ void gemm_q(const bf16x8 Wreg[16], const char* Xb,
                                       f32x4 acc[2][4], int l) {
    const bf16x8* Xf = (const bf16x8*)Xb;
#pragma unroll
    for (int ks = 0; ks < 4; ++ks) {
        bf16x8 Bh[4], Bl[4];
#pragma unroll
        for (int ct = 0; ct < 4; ++ct) {
            Bh[ct] = Xf[((ct*4 + ks)*2 + 0)*64 + l];
            Bl[ct] = Xf[((ct*4 + ks)*2 + 1)*64 + l];
        }
#pragma unroll
        for (int itl = 0; itl < 2; ++itl) {
            const bf16x8 Ah = Wreg[(itl*4 + ks)*2 + 0];
            const bf16x8 Al = Wreg[(itl*4 + ks)*2 + 1];
#pragma unroll
            for (int ct = 0; ct < 4; ++ct) {
                acc[itl][ct] = MF(Ah, Bh[ct], acc[itl][ct]);
                acc[itl][ct] = MF(Ah, Bl[ct], acc[itl][ct]);
                acc[itl][ct] = MF(Al, Bh[ct], acc[itl][ct]);
            }
        }
    }
}

__global__ __launch_bounds__(256, 4) void sofa_mfma6(
    const float* __restrict__ alpha,
    const float* __restrict__ w0, const float* __restrict__ w3,
    const float* __restrict__ b0, const float* __restrict__ b1,
    const float* __restrict__ b2, const float* __restrict__ b3,
    const float* __restrict__ sqrt_a,
    const uint4* __restrict__ ws,
    float* __restrict__ out)
{
    __shared__ char smem[32768];   // X frags: 4 ct * 4 ks * 2 hl * 1024 B
    char*  Xb  = smem;
    float* red = (float*)smem;     // reused after GEMM2 (256 floats)

    const int tile = blockIdx.x, n = blockIdx.y;
    const int tid = threadIdx.x;
    const int l   = tid & 63;
    const int rq  = __builtin_amdgcn_readfirstlane(tid >> 6); // row quarter 0..3
    const int t   = l >> 4;

    const bf16x8* W1f = (const bf16x8*)(ws + n * 4096);
    const bf16x8* W2f = (const bf16x8*)(ws + (128 + n) * 4096);

    // ---- issue W1 prefetch into registers (hidden under layer0 VALU) ----
    bf16x8 Wreg[16];
    loadW16(W1f, Wreg, rq, l);

    // ---- layer 0: elementwise, write X1 frags ----
    {
        const float* w0n = w0 + n * HH;
        const float* b0n = b0 + n * HH;
        const int c  = tid & 63;         // col: <32 h(point c), >=32 dh(point c-32)
        const int jb = tid >> 6;         // kstep 0..3
        int p = tile * BP2 + (c & 31);
        if (p > 2048) p = 2048;
        const float a = alpha[p];
        const bool isdh = c >= 32;
        const int ct = c >> 4;
#pragma unroll
        for (int g8 = 0; g8 < 4; ++g8) {
            const float4 wv4a = *(const float4*)(w0n + jb*32 + g8*8);
            const float4 wv4b = *(const float4*)(w0n + jb*32 + g8*8 + 4);
            const float4 bv4a = *(const float4*)(b0n + jb*32 + g8*8);
            const float4 bv4b = *(const float4*)(b0n + jb*32 + g8*8 + 4);
            const float wvv[8] = {wv4a.x,wv4a.y,wv4a.z,wv4a.w,wv4b.x,wv4b.y,wv4b.z,wv4b.w};
            const float bvv[8] = {bv4a.x,bv4a.y,bv4a.z,bv4a.w,bv4b.x,bv4b.y,bv4b.z,bv4b.w};
            u32 hd[4], ld_[4];
#pragma unroll
            for (int q = 0; q < 4; ++q) {
                float vv[2];
#pragma unroll
                for (int e = 0; e < 2; ++e) {
                    const float wv  = wvv[q*2 + e];
                    const float pre = fmaf(wv, a, bvv[q*2 + e]);
                    const bool  on  = pre > 0.f;
                    vv[e] = isdh ? (on ? wv : 0.f) : (on ? pre : 0.f);
                }
                split_pair(vv[0], vv[1], hd[q], ld_[q]);
            }
            const int lane = g8 * 16 + (c & 15);
            const int fq   = ct * 4 + jb;
            *(uint4*)(Xb + ((fq*2 + 0)*64 + lane)*16) = make_uint4(hd[0], hd[1], hd[2], hd[3]);
            *(uint4*)(Xb + ((fq*2 + 1)*64 + lane)*16) = make_uint4(ld_[0], ld_[1], ld_[2], ld_[3]);
        }
    }
    __syncthreads();

    // ---- GEMM 1 (W1 from registers) ----
    f32x4 acc[2][4];
#pragma unroll
    for (int i0 = 0; i0 < 2; ++i0)
#pragma unroll
        for (int c0 = 0; c0 < 4; ++c0) { f32x4 z = {0.f,0.f,0.f,0.f}; acc[i0][c0] = z; }
    __builtin_amdgcn_s_setprio(1);
    gemm_q(Wreg, Xb, acc, l);
    __builtin_amdgcn_s_setprio(0);

    // ---- issue W2 prefetch (Wreg dead; hidden under transition VALU) ----
    loadW16(W2f, Wreg, rq, l);

    // ---- transition: bias + relu + split/pack X2 in regs ----
    u32 pxh[2][2][2][2], pxd[2][2][2][2];  // [itl][c][hl][dword]
    {
        const float* b1n = b1 + n * HH;
#pragma unroll
        for (int itl = 0; itl < 2; ++itl) {
            const int ibase = (rq*2 + itl)*16 + t*4;
#pragma unroll
            for (int c = 0; c < 2; ++c) {
                float hv[4], dv[4];
#pragma unroll
                for (int r = 0; r < 4; ++r) {
                    const float pre = acc[itl][c][r] + b1n[ibase + r];
                    const bool  on  = pre > 0.f;
                    hv[r] = on ? pre : 0.f;
                    dv[r] = on ? acc[itl][c + 2][r] : 0.f;
                }
                split_pair(hv[0], hv[1], pxh[itl][c][0][0], pxh[itl][c][1][0]);
                split_pair(hv[2], hv[3], pxh[itl][c][0][1], pxh[itl][c][1][1]);
                split_pair(dv[0], dv[1], pxd[itl][c][0][0], pxd[itl][c][1][0]);
                split_pair(dv[2], dv[3], pxd[itl][c][0][1], pxd[itl][c][1][1]);
            }
        }
    }
    __syncthreads();   // all GEMM1 reads of X1 complete

    // ---- write X2 frags ----
    {
#pragma unroll
        for (int itl = 0; itl < 2; ++itl) {
            const int lane = (itl*2 + (t >> 1))*16 + (l & 15);
            const int off8 = (t & 1)*8;
#pragma unroll
            for (int c = 0; c < 2; ++c) {
#pragma unroll
                for (int hl = 0; hl < 2; ++hl) {
                    uint2 vh; vh.x = pxh[itl][c][hl][0]; vh.y = pxh[itl][c][hl][1];
                    *(uint2*)(Xb + (((c    )*4 + rq)*2 + hl)*1024 + lane*16 + off8) = vh;
                    uint2 vd; vd.x = pxd[itl][c][hl][0]; vd.y = pxd[itl][c][hl][1];
                    *(uint2*)(Xb + (((c + 2)*4 + rq)*2 + hl)*1024 + lane*16 + off8) = vd;
                }
            }
        }
    }
    __syncthreads();

    // ---- GEMM 2 (W2 from registers) ----
    f32x4 acc2[2][4];
#pragma unroll
    for (int i0 = 0; i0 < 2; ++i0)
#pragma unroll
        for (int c0 = 0; c0 < 4; ++c0) { f32x4 z = {0.f,0.f,0.f,0.f}; acc2[i0][c0] = z; }
    __builtin_amdgcn_s_setprio(1);
    gemm_q(Wreg, Xb, acc2, l);
    __builtin_amdgcn_s_setprio(0);

    // ---- layer 3: bias+relu then reduce with w3 (partial over this wave's 32 rows) ----
    float sh[2] = {0.f, 0.f}, sd[2] = {0.f, 0.f};
    {
        const float* b2n = b2 + n * HH;
        const float* w3n = w3 + n * HH;
#pragma unroll
        for (int itl = 0; itl < 2; ++itl) {
            const int ibase = (rq*2 + itl)*16 + t*4;
#pragma unroll
            for (int r = 0; r < 4; ++r) {
                const int   i  = ibase + r;
                const float bv = b2n[i];
                const float wv = w3n[i];
#pragma unroll
                for (int c = 0; c < 2; ++c) {
                    const float pre = acc2[itl][c][r] + bv;
                    const bool  on  = pre > 0.f;
                    sh[c] = fmaf(wv, on ? pre : 0.f,                 sh[c]);
                    sd[c] = fmaf(wv, on ? acc2[itl][c + 2][r] : 0.f, sd[c]);
                }
            }
        }
    }
#pragma unroll
    for (int c = 0; c < 2; ++c) {
        sh[c] += __shfl_xor(sh[c], 16); sh[c] += __shfl_xor(sh[c], 32);
        sd[c] += __shfl_xor(sd[c], 16); sd[c] += __shfl_xor(sd[c], 32);
    }
    __syncthreads();   // all GEMM2 X reads done -> reuse LDS as reduction buffer
    if (l < 16) {
#pragma unroll
        for (int c = 0; c < 2; ++c) {
            red[rq * 32 + c * 16 + l]        = sh[c];
            red[128 + rq * 32 + c * 16 + l]  = sd[c];
        }
    }
    __syncthreads();

    // ---- epilogue (32 threads): square + JVP + trig via __sinf + mirror identity ----
    if (tid < 32) {
        float oo = b3[n], d2 = 0.f;
#pragma unroll
        for (int q = 0; q < 4; ++q) {
            oo += red[q * 32 + tid];
            d2 += red[128 + q * 32 + tid];
        }
        const float bb = oo * oo;
        const float db = 2.f * oo * d2;
        const float sa = sqrt_a[n];
        const float af = sa * sa;
        const int   NL = NN * LL;
        const int   k1 = tile * BP2 + tid;
        if (k1 < PH) {
            const float al = alpha[k1];
            const float sn = __sinf(al), cs = __cosf(al);
            const int base = n * LL + k1;
            out[base]          = af * (cs - 1.f);
            out[NL + base]     = bb * sn;
            out[2 * NL + base] = -af * sn;
            out[3 * NL + base] = fmaf(bb, cs, db * sn);
            // mirror half: alpha[4096-k1] = pi - alpha[k1] -> sin same, cos negated
            if (k1 <= PH - 2) {
                const int base2 = n * LL + (LL - 1) - k1;
                out[base2]          = af * (-cs - 1.f);
                out[NL + base2]     = bb * sn;
                out[2 * NL + base2] = -af * sn;
                out[3 * NL + base2] = fmaf(bb, -cs, -db * sn);
            }
        }
    }
}

// =================== fallback (round-4 kernel, used if ws too small) =========

__device__ __forceinline__ void stageW_fb(const float* __restrict__ wn, char* Wb, int tid) {
#pragma unroll
    for (int it = 0; it < 4; ++it) {
        const int s  = tid + it * 512;
        const int l  = s & 63;
        const int fq = s >> 6;
        const int ks = fq & 3, it7 = fq >> 2;
        const int i  = it7 * 16 + (l & 15);
        const int k0 = ks * 32 + (l >> 4) * 8;
        const float4* src = (const float4*)(wn + i * HH + k0);
        const float4 va = src[0], vb = src[1];
        const float v[8] = {va.x, va.y, va.z, va.w, vb.x, vb.y, vb.z, vb.w};
        u32 hd[4], ld_[4];
#pragma unroll
        for (int q = 0; q < 4; ++q) {
            u32 h0, l0, h1, l1;
            split1(v[2*q], h0, l0); split1(v[2*q+1], h1, l1);
            hd[q]  = h0 | (h1 << 16);
            ld_[q] = l0 | (l1 << 16);
        }
        *(uint4*)(Wb + (((fq*2)+0)*64 + l)*16) = make_uint4(hd[0], hd[1], hd[2], hd[3]);
        *(uint4*)(Wb + (((fq*2)+1)*64 + l)*16) = make_uint4(ld_[0], ld_[1], ld_[2], ld_[3]);
    }
}

__device__ __forceinline__ void gemm128_fb(const char* Wb, const char* Xb,
                                           f32x4 acc[4][2], int rw, int cw, int l) {
    const bf16x8* Wf = (const bf16x8*)Wb;
    const bf16x8* Xf = (const bf16x8*)Xb;
#pragma unroll
    for (int ks = 0; ks < 4; ++ks) {
        bf16x8 Bh[2], Bl[2];
#pragma unroll
        for (int cg = 0; cg < 2; ++cg) {
            const int ct = cw + cg * 4;
            Bh[cg] = Xf[((ct*4 + ks)*2 + 0)*64 + l];
            Bl[cg] = Xf[((ct*4 + ks)*2 + 1)*64 + l];
        }
#pragma unroll
        for (int itl = 0; itl < 4; ++itl) {
            const int IT = rw * 4 + itl;
            const bf16x8 Ah = Wf[((IT*4 + ks)*2 + 0)*64 + l];
            const bf16x8 Al = Wf[((IT*4 + ks)*2 + 1)*64 + l];
#pragma unroll
            for (int cg = 0; cg < 2; ++cg) {
                acc[itl][cg] = MF(Ah, Bh[cg], acc[itl][cg]);
                acc[itl][cg] = MF(Ah, Bl[cg], acc[itl][cg]);
                acc[itl][cg] = MF(Al, Bh[cg], acc[itl][cg]);
            }
        }
    }
}

__global__ __launch_bounds__(512, 2) void sofa_mfma_fb(
    const float* __restrict__ alpha,
    const float* __restrict__ w0, const float* __restrict__ w1,
    const float* __restrict__ w2, const float* __restrict__ w3,
    const float* __restrict__ b0, const float* __restrict__ b1,
    const float* __restrict__ b2, const float* __restrict__ b3,
    const float* __restrict__ sqrt_a,
    float* __restrict__ out)
{
    __shared__ char smem[131072];
    char* Wb = smem;
    char* Xb = smem + 65536;
    float* red = (float*)smem;

    const int tile = blockIdx.x, n = blockIdx.y;
    const int tid = threadIdx.x;
    const int l   = tid & 63;
    const int w   = tid >> 6;
    const int rw  = w & 1;
    const int cw  = w >> 1;
    const int t   = l >> 4;

    stageW_fb(w1 + n * HH * HH, Wb, tid);
    {
        const float* w0n = w0 + n * HH;
        const float* b0n = b0 + n * HH;
        const int c  = tid & 127;
        const int jb = tid >> 7;
        int p = tile * BP + (c & 63);
        if (p > 2048) p = 2048;
        const float a = alpha[p];
        const bool isdh = c >= 64;
        const int ct = c >> 4;
#pragma unroll
        for (int g8 = 0; g8 < 4; ++g8) {
            u32 hd[4], ld_[4];
#pragma unroll
            for (int q = 0; q < 4; ++q) {
                float vv[2];
#pragma unroll
                for (int e = 0; e < 2; ++e) {
                    const int j = jb * 32 + g8 * 8 + q * 2 + e;
                    const float wv  = w0n[j];
                    const float pre = fmaf(wv, a, b0n[j]);
                    const bool  on  = pre > 0.f;
                    vv[e] = isdh ? (on ? wv : 0.f) : (on ? pre : 0.f);
                }
                u32 h0, l0, h1, l1;
                split1(vv[0], h0, l0); split1(vv[1], h1, l1);
                hd[q]  = h0 | (h1 << 16);
                ld_[q] = l0 | (l1 << 16);
            }
            const int lane = g8 * 16 + (c & 15);
            const int fq   = ct * 4 + jb;
            *(uint4*)(Xb + ((fq*2 + 0)*64 + lane)*16) = make_uint4(hd[0], hd[1], hd[2], hd[3]);
            *(uint4*)(Xb + ((fq*2 + 1)*64 + lane)*16) = make_uint4(ld_[0], ld_[1], ld_[2], ld_[3]);
        }
    }
    __syncthreads();

    f32x4 acc[4][2];
#pragma unroll
    for (int i0 = 0; i0 < 4; ++i0)
#pragma unroll
        for (int c0 = 0; c0 < 2; ++c0) { f32x4 z = {0.f,0.f,0.f,0.f}; acc[i0][c0] = z; }
    gemm128_fb(Wb, Xb, acc, rw, cw, l);

    u32 px[4][2][2][2];
    {
        const float* b1n = b1 + n * HH;
#pragma unroll
        for (int itl = 0; itl < 4; ++itl) {
            const int ibase = (rw*4 + itl)*16 + t*4;
            float hv[4], dv[4];
#pragma unroll
            for (int r = 0; r < 4; ++r) {
                const float pre = acc[itl][0][r] + b1n[ibase + r];
                const bool  on  = pre > 0.f;
                hv[r] = on ? pre : 0.f;
                dv[r] = on ? acc[itl][1][r] : 0.f;
            }
#pragma unroll
            for (int cg = 0; cg < 2; ++cg) {
                const float* vs = cg ? dv : hv;
                u32 a0,c0,a1,c1,a2,c2,a3,c3;
                split1(vs[0],a0,c0); split1(vs[1],a1,c1);
                split1(vs[2],a2,c2); split1(vs[3],a3,c3);
                px[itl][cg][0][0] = a0 | (a1 << 16);
                px[itl][cg][0][1] = a2 | (a3 << 16);
                px[itl][cg][1][0] = c0 | (c1 << 16);
                px[itl][cg][1][1] = c2 | (c3 << 16);
            }
        }
    }
    __syncthreads();

    stageW_fb(w2 + n * HH * HH, Wb, tid);
    {
#pragma unroll
        for (int itl = 0; itl < 4; ++itl) {
            const int IT   = rw*4 + itl;
            const int lane = ((IT & 1)*2 + (t >> 1))*16 + (l & 15);
            const int off8 = (t & 1)*8;
            const int ksn  = IT >> 1;
#pragma unroll
            for (int cg = 0; cg < 2; ++cg) {
                const int fq = (cw + cg*4)*4 + ksn;
#pragma unroll
                for (int hl = 0; hl < 2; ++hl) {
                    uint2 vv; vv.x = px[itl][cg][hl][0]; vv.y = px[itl][cg][hl][1];
                    *(uint2*)(Xb + ((fq*2 + hl)*64 + lane)*16 + off8) = vv;
                }
            }
        }
    }
    __syncthreads();

    f32x4 acc2[4][2];
#pragma unroll
    for (int i0 = 0; i0 < 4; ++i0)
#pragma unroll
        for (int c0 = 0; c0 < 2; ++c0) { f32x4 z = {0.f,0.f,0.f,0.f}; acc2[i0][c0] = z; }
    gemm128_fb(Wb, Xb, acc2, rw, cw, l);

    float sh = 0.f, sd = 0.f;
    {
        const float* b2n = b2 + n * HH;
        const float* w3n = w3 + n * HH;
#pragma unroll
        for (int itl = 0; itl < 4; ++itl) {
            const int ibase = (rw*4 + itl)*16 + t*4;
#pragma unroll
            for (int r = 0; r < 4; ++r) {
                const int   i   = ibase + r;
                const float pre = acc2[itl][0][r] + b2n[i];
                const bool  on  = pre > 0.f;
                const float hv  = on ? pre : 0.f;
                const float dv  = on ? acc2[itl][1][r] : 0.f;
                const float wv  = w3n[i];
                sh = fmaf(wv, hv, sh);
                sd = fmaf(wv, dv, sd);
            }
        }
    }
    sh += __shfl_xor(sh, 16); sh += __shfl_xor(sh, 32);
    sd += __shfl_xor(sd, 16); sd += __shfl_xor(sd, 32);
    __syncthreads();
    if (t == 0) {
        const int p = cw * 16 + (l & 15);
        red[rw * 64 + p]        = sh;
        red[128 + rw * 64 + p]  = sd;
    }
    __syncthreads();

    if (tid < 64) {
        const float oo = b3[n] + red[tid] + red[64 + tid];
        const float d2 = red[128 + tid] + red[192 + tid];
        const float bb = oo * oo;
        const float db = 2.f * oo * d2;
        const float sa = sqrt_a[n];
        const float af = sa * sa;
        const int   NL = NN * LL;
        const int   k1 = tile * BP + tid;
        if (k1 < PH) {
            {
                const float al = alpha[k1];
                const float sn = sinf(al), cs = cosf(al);
                const int base = n * LL + k1;
                out[base]          = af * (cs - 1.f);
                out[NL + base]     = bb * sn;
                out[2 * NL + base] = -af * sn;
                out[3 * NL + base] = fmaf(bb, cs, db * sn);
            }
            if (k1 <= PH - 2) {
                const int   k2  = (LL - 1) - k1;
                const float al2 = alpha[k2];
                const float sn2 = sinf(al2), cs2 = cosf(al2);
                const int base2 = n * LL + k2;
                out[base2]          = af * (cs2 - 1.f);
                out[NL + base2]     = bb * sn2;
                out[2 * NL + base2] = -af * sn2;
                out[3 * NL + base2] = fmaf(bb, cs2, -db * sn2);
            }
        }
    }
}

extern "C" void kernel_launch(void* const* d_in, const int* in_sizes, int n_in,
                              void* d_out, int out_size, void* d_ws, size_t ws_size,
                              hipStream_t stream) {
    const float* alpha  = (const float*)d_in[0];
    const float* w0     = (const float*)d_in[1];
    const float* w1     = (const float*)d_in[2];
    const float* w2     = (const float*)d_in[3];
    const float* w3     = (const float*)d_in[4];
    const float* b0     = (const float*)d_in[5];
    const float* b1     = (const float*)d_in[6];
    const float* b2     = (const float*)d_in[7];
    const float* b3     = (const float*)d_in[8];
    const float* sqrt_a = (const float*)d_in[9];
    (void)in_sizes; (void)n_in; (void)out_size;

    if (ws_size >= (size_t)WS_NEEDED) {
        uint4* ws = (uint4*)d_ws;
        presplit2<<<256, 512, 0, stream>>>(w1, w2, ws);
        dim3 grid(NT2, NN);
        sofa_mfma6<<<grid, 256, 0, stream>>>(alpha, w0, w3, b0, b1, b2, b3,
                                             sqrt_a, ws, (float*)d_out);
    } else {
        dim3 grid(NTILE, NN);
        sofa_mfma_fb<<<grid, 512, 0, stream>>>(alpha, w0, w1, w2, w3,
                                               b0, b1, b2, b3, sqrt_a,
                                               (float*)d_out);
    }
}